// Round 3
// baseline (325.387 us; speedup 1.0000x reference)
//
#include <hip/hip_runtime.h>
#include <hip/hip_bf16.h>

// HamGraphConvolution: N=100k nodes, D=64 feats, H=4 heads (DK=16), E=1.6M edges.
// xt = c1*x + c2*(x@W^T)  (Hamiltonian 4-step linear recurrence folded on host)
// GAT-style attention normalized over col, aggregated over row.
// Softmax max-subtraction skipped: shift-invariant, eps 1e-16 unreachable.
// R11: xt stored bf16 (halves gather traffic), scores fp32.
// R12 FAILED (block-per-bucket fused aggr, 12x slower): collapsed TLP to 6.2K
//     waves with serial per-wave latency chains. Reverted.
// R13: k_aggr 4x16-lane groups, 32 edges in flight, no serial tail: 53->50us.
// R14: k_aggr polish: (a) slot loops gated by k<nk (wave-uniform skip) -- mean
//     degree 16 means nk=4 of 8, so half the fma/cvt issue was padding;
//     (b) 4 rows per wave serially (grid 25k->6250 blocks): occupancy was 67%
//     at VGPR=24/LDS=0 (resource-wise 100% possible) -> dispatch/ramp bound;
//     rowptr loaded once per wave (coalesced + shfl).

#define LRELU(v) ((v) > 0.0f ? (v) : 0.2f * (v))

#define EC 4096      // edges per hist/scatter block
#define BSC 256      // col-bucket size (shift 8)
#define BSR 128      // row-bucket size (shift 7)
#define NPW 8        // nodes per wave in k_node
#define NPB 32       // nodes per block (4 waves)
#define RPW 4        // rows per wave in k_aggr

__device__ __forceinline__ float bf16_to_f32(unsigned short u) {
    return __uint_as_float((unsigned int)u << 16);
}
__device__ __forceinline__ unsigned short f32_to_bf16(float f) {
    __hip_bfloat16 h = __float2bfloat16(f);  // RTN
    return *reinterpret_cast<unsigned short*>(&h);
}

__global__ __launch_bounds__(256) void k_node(const float* __restrict__ x,
                                              const float* __restrict__ W,
                                              const float* __restrict__ a,
                                              unsigned short* __restrict__ xt16,
                                              float* __restrict__ s_src,
                                              float* __restrict__ s_dst,
                                              int n, float c1, float c2) {
    __shared__ float Ws[64 * 68];   // pad 68: float4-aligned rows
    __shared__ float xs[NPB * 64];  // x-tile: 8 KB
    int t = threadIdx.x;
    for (int i = t; i < 64 * 64; i += 256)
        Ws[(i >> 6) * 68 + (i & 63)] = W[i];
    {
        size_t gbase = (size_t)blockIdx.x * NPB * 64;
        for (int i = t; i < NPB * 64; i += 256) {
            size_t g = gbase + i;
            xs[i] = (g < (size_t)n * 64) ? x[g] : 0.0f;  // coalesced
        }
    }
    __syncthreads();
    int wave = t >> 6;
    int lane = t & 63;
    float a_s = a[lane & 15];
    float a_d = a[16 + (lane & 15)];
    int nbase = blockIdx.x * NPB + wave * NPW;
    const float* xw = xs + wave * NPW * 64;

    float p[NPW];
#pragma unroll
    for (int j = 0; j < NPW; ++j) p[j] = 0.0f;

#pragma unroll 2
    for (int k4 = 0; k4 < 64; k4 += 4) {
        // per-lane W row segment (b128); x reads are wave-uniform -> broadcast
        float4 wr = *(const float4*)(Ws + lane * 68 + k4);
#pragma unroll
        for (int j = 0; j < NPW; ++j) {
            float4 xb = *(const float4*)(xw + j * 64 + k4);
            p[j] = fmaf(xb.x, wr.x, p[j]);
            p[j] = fmaf(xb.y, wr.y, p[j]);
            p[j] = fmaf(xb.z, wr.z, p[j]);
            p[j] = fmaf(xb.w, wr.w, p[j]);
        }
    }

#pragma unroll
    for (int j = 0; j < NPW; ++j) {  // constant j: p[] scalarizes
        int node = nbase + j;
        if (node < n) {
            float xv = xw[j * 64 + lane];
            float xtv = c1 * xv + c2 * p[j];
            xt16[(size_t)node * 64 + lane] = f32_to_bf16(xtv);
            float ss = xtv * a_s;  // scores stay fp32
            float sd = xtv * a_d;
#pragma unroll
            for (int off = 8; off >= 1; off >>= 1) {
                ss += __shfl_xor(ss, off, 64);
                sd += __shfl_xor(sd, off, 64);
            }
            if ((lane & 15) == 0) {
                int h = lane >> 4;
                s_src[node * 4 + h] = ss;
                s_dst[node * 4 + h] = sd;
            }
        }
    }
}

// per-block LDS histograms of row>>7 and col>>8; H layout [bucket][block]
__global__ __launch_bounds__(256) void k_hist(const int* __restrict__ row,
                                              const int* __restrict__ col,
                                              int* __restrict__ Hr,
                                              int* __restrict__ Hc,
                                              int e, int nblk, int nbr, int nbc) {
    __shared__ int hr[1024];
    __shared__ int hc[512];
    int t = threadIdx.x;
    for (int i = t; i < 1024; i += 256) hr[i] = 0;
    for (int i = t; i < 512; i += 256) hc[i] = 0;
    __syncthreads();
    int base = blockIdx.x * EC;
#pragma unroll
    for (int j = 0; j < EC / 256; ++j) {
        int i = base + t + j * 256;
        if (i < e) {
            atomicAdd(&hr[row[i] >> 7], 1);
            atomicAdd(&hc[col[i] >> 8], 1);
        }
    }
    __syncthreads();
    for (int b = t; b < nbr; b += 256) Hr[(size_t)b * nblk + blockIdx.x] = hr[b];
    for (int b = t; b < nbc; b += 256) Hc[(size_t)b * nblk + blockIdx.x] = hc[b];
}

// fused: exclusive scan of Hr rows (blocks [0,nbr)) and Hc rows (blocks
// [nbr, nbr+nbc)); per-bucket totals to BtotR/BtotC. nblk<=512.
__global__ __launch_bounds__(256) void k_scanH2(int* __restrict__ Hr,
                                                int* __restrict__ Hc,
                                                int* __restrict__ BtotR,
                                                int* __restrict__ BtotC,
                                                int nblk, int nbr) {
    __shared__ int vals[512];
    __shared__ int part[256];
    int t = threadIdx.x;
    int bb = blockIdx.x;
    int* Hb;
    int* Btot;
    if (bb < nbr) {
        Hb = Hr + (size_t)bb * nblk;
        Btot = BtotR + bb;
    } else {
        Hb = Hc + (size_t)(bb - nbr) * nblk;
        Btot = BtotC + (bb - nbr);
    }
    for (int i = t; i < nblk; i += 256) vals[i] = Hb[i];
    __syncthreads();
    int c0 = t * 2;
    int s = 0;
#pragma unroll
    for (int j = 0; j < 2; ++j)
        if (c0 + j < nblk) s += vals[c0 + j];
    part[t] = s;
    __syncthreads();
    for (int d = 1; d < 256; d <<= 1) {
        int add = (t >= d) ? part[t - d] : 0;
        __syncthreads();
        part[t] += add;
        __syncthreads();
    }
    int run = part[t] - s;
#pragma unroll
    for (int j = 0; j < 2; ++j) {
        int i = c0 + j;
        if (i < nblk) {
            int v = vals[i];
            Hb[i] = run;
            run += v;
        }
    }
    if (t == 255) *Btot = part[255];
}

// fused: block 0 scans BtotR->BbR, block 1 scans BtotC->BbC
__global__ __launch_bounds__(256) void k_base2(const int* __restrict__ BtotR,
                                               int* __restrict__ BbR, int nbr,
                                               const int* __restrict__ BtotC,
                                               int* __restrict__ BbC, int nbc) {
    const int* Btot = (blockIdx.x == 0) ? BtotR : BtotC;
    int* Bbase = (blockIdx.x == 0) ? BbR : BbC;
    int nb = (blockIdx.x == 0) ? nbr : nbc;
    __shared__ int part[256];
    __shared__ int carry;
    int t = threadIdx.x;
    if (t == 0) carry = 0;
    __syncthreads();
    for (int base = 0; base < nb; base += 256) {
        int i = base + t;
        int v = (i < nb) ? Btot[i] : 0;
        part[t] = v;
        __syncthreads();
        for (int d = 1; d < 256; d <<= 1) {
            int add = (t >= d) ? part[t - d] : 0;
            __syncthreads();
            part[t] += add;
            __syncthreads();
        }
        if (i < nb) Bbase[i] = carry + part[t] - v;
        __syncthreads();
        if (t == 0) carry += part[255];
        __syncthreads();
    }
    if (t == 0) Bbase[nb] = carry;
}

// scatter edges into c-bucketed ebc (payload r<<8|c_low) and r-bucketed ebr
// (payload c<<7|r_low) using LDS cursors; plain stores, no global atomics
__global__ __launch_bounds__(256) void k_scatter_dual(
    const int* __restrict__ row, const int* __restrict__ col,
    const int* __restrict__ Hr, const int* __restrict__ Hc,
    const int* __restrict__ BbR, const int* __restrict__ BbC,
    int* __restrict__ ebr, int* __restrict__ ebc,
    int e, int nblk, int nbr, int nbc) {
    __shared__ int curr[1024];
    __shared__ int curc[512];
    int t = threadIdx.x;
    int blk = blockIdx.x;
    for (int b = t; b < nbr; b += 256) curr[b] = BbR[b] + Hr[(size_t)b * nblk + blk];
    for (int b = t; b < nbc; b += 256) curc[b] = BbC[b] + Hc[(size_t)b * nblk + blk];
    __syncthreads();
    int base = blk * EC;
#pragma unroll
    for (int j = 0; j < EC / 256; ++j) {
        int i = base + t + j * 256;
        if (i < e) {
            int r = row[i], c = col[i];
            int pr = atomicAdd(&curr[r >> 7], 1);
            ebr[pr] = (c << 7) | (r & 127);
            int pc = atomicAdd(&curc[c >> 8], 1);
            ebc[pc] = (r << 8) | (c & 255);
        }
    }
}

// block per col-bucket: exp sums into LDS, write rden (no global atomics)
__global__ __launch_bounds__(256) void k_denom_b(const int* __restrict__ ebc,
                                                 const int* __restrict__ BbC,
                                                 const float* __restrict__ s_src,
                                                 const float* __restrict__ s_dst,
                                                 float* __restrict__ rden, int n) {
    __shared__ float acc[BSC * 4];
    __shared__ float sd[BSC * 4];
    int t = threadIdx.x;
    int b = blockIdx.x;
    int cbase = b << 8;
    for (int i = t; i < BSC * 4; i += 256) {
        acc[i] = 0.0f;
        int c4 = cbase * 4 + i;
        sd[i] = (c4 < n * 4) ? s_dst[c4] : 0.0f;
    }
    __syncthreads();
    int start = BbC[b], end = BbC[b + 1];
    for (int i = start + t; i < end; i += 256) {
        int p = ebc[i];
        int r = p >> 8, cl = p & 255;
        float4 ss = *(const float4*)(s_src + (size_t)r * 4);
        atomicAdd(&acc[cl * 4 + 0], __expf(LRELU(ss.x + sd[cl * 4 + 0])));
        atomicAdd(&acc[cl * 4 + 1], __expf(LRELU(ss.y + sd[cl * 4 + 1])));
        atomicAdd(&acc[cl * 4 + 2], __expf(LRELU(ss.z + sd[cl * 4 + 2])));
        atomicAdd(&acc[cl * 4 + 3], __expf(LRELU(ss.w + sd[cl * 4 + 3])));
    }
    __syncthreads();
    for (int i = t; i < BSC * 4; i += 256) {
        int c4 = cbase * 4 + i;
        if (c4 < n * 4) rden[c4] = 1.0f / (acc[i] + 1e-16f);
    }
}

// level-2 counting sort within row-bucket: ebr -> row-sorted packed int2{c,w},
// writes global rowptr; w computed here (thread-per-edge, independent loads)
__global__ __launch_bounds__(256) void k_sort2(const int* __restrict__ ebr,
                                               const int* __restrict__ BbR,
                                               const float* __restrict__ s_src,
                                               const float* __restrict__ s_dst,
                                               const float* __restrict__ rden,
                                               int* __restrict__ rowptr,
                                               int2* __restrict__ cwp,
                                               int n, int e) {
    __shared__ int cnt[BSR];
    __shared__ int pfx[BSR];
    __shared__ int cur[BSR];
    __shared__ float ssh[BSR * 4];
    int t = threadIdx.x;
    int b = blockIdx.x;
    int rbase = b << 7;
    if (t < BSR) cnt[t] = 0;
    for (int i = t; i < BSR * 4; i += 256) {
        int g = rbase * 4 + i;
        ssh[i] = (g < n * 4) ? s_src[g] : 0.0f;
    }
    __syncthreads();
    int start = BbR[b], end = BbR[b + 1];
    for (int i = start + t; i < end; i += 256)
        atomicAdd(&cnt[ebr[i] & 127], 1);
    __syncthreads();
    if (t < BSR) pfx[t] = cnt[t];
    __syncthreads();
    for (int d = 1; d < BSR; d <<= 1) {
        int v = (t < BSR && t >= d) ? pfx[t - d] : 0;
        __syncthreads();
        if (t < BSR) pfx[t] += v;
        __syncthreads();
    }
    if (t < BSR) {
        int excl = start + pfx[t] - cnt[t];
        cur[t] = excl;
        int r = rbase + t;
        if (r < n) rowptr[r] = excl;
    }
    if (b == 0 && t == 0) rowptr[n] = e;
    __syncthreads();
    for (int i = start + t; i < end; i += 256) {
        int p = ebr[i];
        int rl = p & 127, c = p >> 7;
        float4 sd = *(const float4*)(s_dst + (size_t)c * 4);
        float4 rd = *(const float4*)(rden + (size_t)c * 4);
        float wv = __expf(LRELU(ssh[rl * 4 + 0] + sd.x)) * rd.x +
                   __expf(LRELU(ssh[rl * 4 + 1] + sd.y)) * rd.y +
                   __expf(LRELU(ssh[rl * 4 + 2] + sd.z)) * rd.z +
                   __expf(LRELU(ssh[rl * 4 + 3] + sd.w)) * rd.w;
        int pos = atomicAdd(&cur[rl], 1);
        cwp[pos] = make_int2(c, __float_as_int(0.25f * wv));  // one 8B store
    }
}

// R14 wave-per-row CSR gather-reduce: 4x16-lane groups, 4 edges per load instr
// (ushort4 8B/lane), up to 32 edges in flight; slot loops gated by k<nk
// (wave-uniform) so padded slots cost nothing; 4 rows per wave serially.
__global__ __launch_bounds__(256) void k_aggr(const int* __restrict__ rowptr,
                                              const int2* __restrict__ cwp,
                                              const unsigned short* __restrict__ xt16,
                                              float* __restrict__ out, int n, int e) {
    int wid = blockIdx.x * 4 + (threadIdx.x >> 6);
    int r0 = wid * RPW;
    if (r0 >= n) return;
    int lane = threadIdx.x & 63;
    int g = lane >> 4;   // edge group 0..3
    int l = lane & 15;   // covers cols [l*4, l*4+4)
    // one coalesced load of rowptr[r0..r0+RPW] (lanes 0..RPW), broadcast later
    int rp = rowptr[min(r0 + min(lane, RPW), n)];
    for (int j = 0; j < RPW; ++j) {
        int r = r0 + j;
        if (r >= n) break;
        int start = __shfl(rp, j, 64);
        int end = __shfl(rp, j + 1, 64);
        float4 acc = {0.0f, 0.0f, 0.0f, 0.0f};
        for (int base = start; base < end; base += 32) {
            int m = end - base;
            if (m > 32) m = 32;
            int nk = (m + 3) >> 2;  // slots needed (wave-uniform)
            ushort4 u[8];
            float wv[8];
#pragma unroll
            for (int k = 0; k < 8; ++k) {
                if (k < nk) {
                    int idx = base + k * 4 + g;
                    int idc = idx < e ? idx : e - 1;  // stay in-buffer
                    int2 cw = cwp[idc];               // 8B meta, broadcast in group
                    wv[k] = (idx < end) ? __int_as_float(cw.y) : 0.0f;
                    u[k] = *(const ushort4*)(xt16 + (size_t)cw.x * 64 + l * 4);
                }
            }
#pragma unroll
            for (int k = 0; k < 8; ++k) {
                if (k < nk) {
                    acc.x = fmaf(wv[k], bf16_to_f32(u[k].x), acc.x);
                    acc.y = fmaf(wv[k], bf16_to_f32(u[k].y), acc.y);
                    acc.z = fmaf(wv[k], bf16_to_f32(u[k].z), acc.z);
                    acc.w = fmaf(wv[k], bf16_to_f32(u[k].w), acc.w);
                }
            }
        }
        // combine the 4 groups' partial sums (lane bits 4,5)
        acc.x += __shfl_xor(acc.x, 16, 64);
        acc.y += __shfl_xor(acc.y, 16, 64);
        acc.z += __shfl_xor(acc.z, 16, 64);
        acc.w += __shfl_xor(acc.w, 16, 64);
        acc.x += __shfl_xor(acc.x, 32, 64);
        acc.y += __shfl_xor(acc.y, 32, 64);
        acc.z += __shfl_xor(acc.z, 32, 64);
        acc.w += __shfl_xor(acc.w, 32, 64);
        if (lane < 16) *(float4*)(out + (size_t)r * 64 + l * 4) = acc;
    }
}

extern "C" void kernel_launch(void* const* d_in, const int* in_sizes, int n_in,
                              void* d_out, int out_size, void* d_ws, size_t ws_size,
                              hipStream_t stream) {
    const float* x = (const float*)d_in[0];
    const int* ei = (const int*)d_in[1];
    // d_in[2] = edge_weight: unused by the reference
    const float* W = (const float*)d_in[3];
    const float* a = (const float*)d_in[4];
    int n = in_sizes[0] / 64;
    int e = in_sizes[1] / 2;
    const int* row = ei;
    const int* col = ei + e;
    float* out = (float*)d_out;

    int nblk = (e + EC - 1) / EC;       // 391 (<=512 for k_scanH2)
    int nbr = (n + BSR - 1) / BSR;      // 782 (<=1024)
    int nbc = (n + BSC - 1) / BSC;      // 391 (<=512)

    size_t o = 0;
    auto take = [&](size_t cnt) {
        size_t p = o;
        o += (cnt + 3) & ~(size_t)3;
        return p;
    };
    int* wsi = (int*)d_ws;
    unsigned short* xt16 = (unsigned short*)(wsi + take((size_t)n * 32));  // n*64 bf16
    float* s_src = (float*)(wsi + take((size_t)n * 4));
    float* s_dst = (float*)(wsi + take((size_t)n * 4));
    float* rden = (float*)(wsi + take((size_t)n * 4));
    int* Hr = wsi + take((size_t)nbr * nblk);
    int* Hc = wsi + take((size_t)nbc * nblk);
    int* BtotR = wsi + take(nbr);
    int* BbR = wsi + take(nbr + 1);
    int* BtotC = wsi + take(nbc);
    int* BbC = wsi + take(nbc + 1);
    int* ebr = wsi + take(e);
    int* cwbuf = wsi + take((size_t)2 * e);  // first e ints double as ebc
    int* ebc = cwbuf;            // dead after k_denom_b; k_sort2 overwrites as int2
    int2* cwp = (int2*)cwbuf;
    int* rowptr = wsi + take(n + 1);

    // Fold 4-step (q,p) <- (q+0.25p, p-0.25q): xt = aq*x + bq*(x@W^T)
    float aq = 1.f, bq = 0.f, ap = 0.f, bp = 1.f;
    for (int i = 0; i < 4; ++i) {
        float naq = aq + 0.25f * ap, nbq = bq + 0.25f * bp;
        float nap = ap - 0.25f * aq, nbp = bp - 0.25f * bq;
        aq = naq; bq = nbq; ap = nap; bp = nbp;
    }

    k_node<<<(n + NPB - 1) / NPB, 256, 0, stream>>>(x, W, a, xt16, s_src, s_dst,
                                                    n, aq, bq);
    k_hist<<<nblk, 256, 0, stream>>>(row, col, Hr, Hc, e, nblk, nbr, nbc);
    k_scanH2<<<nbr + nbc, 256, 0, stream>>>(Hr, Hc, BtotR, BtotC, nblk, nbr);
    k_base2<<<2, 256, 0, stream>>>(BtotR, BbR, nbr, BtotC, BbC, nbc);
    k_scatter_dual<<<nblk, 256, 0, stream>>>(row, col, Hr, Hc, BbR, BbC,
                                             ebr, ebc, e, nblk, nbr, nbc);
    k_denom_b<<<nbc, 256, 0, stream>>>(ebc, BbC, s_src, s_dst, rden, n);
    k_sort2<<<nbr, 256, 0, stream>>>(ebr, BbR, s_src, s_dst, rden,
                                     rowptr, cwp, n, e);
    k_aggr<<<(n + RPW * 4 - 1) / (RPW * 4), 256, 0, stream>>>(rowptr, cwp, xt16,
                                                              out, n, e);
}

// Round 4
// 308.349 us; speedup vs baseline: 1.0553x; 1.0553x over previous
//
#include <hip/hip_runtime.h>
#include <hip/hip_bf16.h>

// HamGraphConvolution: N=100k nodes, D=64 feats, H=4 heads (DK=16), E=1.6M edges.
// xt = c1*x + c2*(x@W^T)  (Hamiltonian 4-step linear recurrence folded on host)
// GAT-style attention normalized over col, aggregated over row.
// Softmax max-subtraction skipped: shift-invariant, eps 1e-16 unreachable.
// R11: xt stored bf16 (halves gather traffic), scores fp32.
// R12 FAILED (block-per-bucket fused aggr, 12x slower): collapsed TLP to 6.2K
//     waves with serial per-wave latency chains. Reverted.
// R13: k_aggr 4x16-lane groups, 32 edges in flight, no serial tail: 53->50us.
// R14 FAILED (4 rows/wave serial): wave count 4x down -> latency-bound kernel
//     starved (VALU 50->30%, dur +20%). Wave-per-row parallelism is sacred.
// R15: wave-per-row kept; 8 groups x 8 lanes, 16B/lane (uint4 = 8 bf16):
//     one gather instr covers 8 edges (addr VALU per edge halved, VMEM instr
//     halved); cwp.x stored pre-shifted (c<<6) so gather offset is one 32-bit
//     add; 4 slots gated by k<nk (deg-16 row -> nk=2, padding costs nothing).

#define LRELU(v) ((v) > 0.0f ? (v) : 0.2f * (v))

#define EC 4096      // edges per hist/scatter block
#define BSC 256      // col-bucket size (shift 8)
#define BSR 128      // row-bucket size (shift 7)
#define NPW 8        // nodes per wave in k_node
#define NPB 32       // nodes per block (4 waves)
#define SLOTS 4      // unrolled edge slots in k_aggr (8 edges each)

__device__ __forceinline__ float bf16_to_f32(unsigned short u) {
    return __uint_as_float((unsigned int)u << 16);
}
__device__ __forceinline__ float bflo(unsigned int u) {
    return __uint_as_float(u << 16);
}
__device__ __forceinline__ float bfhi(unsigned int u) {
    return __uint_as_float(u & 0xFFFF0000u);
}
__device__ __forceinline__ unsigned short f32_to_bf16(float f) {
    __hip_bfloat16 h = __float2bfloat16(f);  // RTN
    return *reinterpret_cast<unsigned short*>(&h);
}

__global__ __launch_bounds__(256) void k_node(const float* __restrict__ x,
                                              const float* __restrict__ W,
                                              const float* __restrict__ a,
                                              unsigned short* __restrict__ xt16,
                                              float* __restrict__ s_src,
                                              float* __restrict__ s_dst,
                                              int n, float c1, float c2) {
    __shared__ float Ws[64 * 68];   // pad 68: float4-aligned rows
    __shared__ float xs[NPB * 64];  // x-tile: 8 KB
    int t = threadIdx.x;
    for (int i = t; i < 64 * 64; i += 256)
        Ws[(i >> 6) * 68 + (i & 63)] = W[i];
    {
        size_t gbase = (size_t)blockIdx.x * NPB * 64;
        for (int i = t; i < NPB * 64; i += 256) {
            size_t g = gbase + i;
            xs[i] = (g < (size_t)n * 64) ? x[g] : 0.0f;  // coalesced
        }
    }
    __syncthreads();
    int wave = t >> 6;
    int lane = t & 63;
    float a_s = a[lane & 15];
    float a_d = a[16 + (lane & 15)];
    int nbase = blockIdx.x * NPB + wave * NPW;
    const float* xw = xs + wave * NPW * 64;

    float p[NPW];
#pragma unroll
    for (int j = 0; j < NPW; ++j) p[j] = 0.0f;

#pragma unroll 2
    for (int k4 = 0; k4 < 64; k4 += 4) {
        // per-lane W row segment (b128); x reads are wave-uniform -> broadcast
        float4 wr = *(const float4*)(Ws + lane * 68 + k4);
#pragma unroll
        for (int j = 0; j < NPW; ++j) {
            float4 xb = *(const float4*)(xw + j * 64 + k4);
            p[j] = fmaf(xb.x, wr.x, p[j]);
            p[j] = fmaf(xb.y, wr.y, p[j]);
            p[j] = fmaf(xb.z, wr.z, p[j]);
            p[j] = fmaf(xb.w, wr.w, p[j]);
        }
    }

#pragma unroll
    for (int j = 0; j < NPW; ++j) {  // constant j: p[] scalarizes
        int node = nbase + j;
        if (node < n) {
            float xv = xw[j * 64 + lane];
            float xtv = c1 * xv + c2 * p[j];
            xt16[(size_t)node * 64 + lane] = f32_to_bf16(xtv);
            float ss = xtv * a_s;  // scores stay fp32
            float sd = xtv * a_d;
#pragma unroll
            for (int off = 8; off >= 1; off >>= 1) {
                ss += __shfl_xor(ss, off, 64);
                sd += __shfl_xor(sd, off, 64);
            }
            if ((lane & 15) == 0) {
                int h = lane >> 4;
                s_src[node * 4 + h] = ss;
                s_dst[node * 4 + h] = sd;
            }
        }
    }
}

// per-block LDS histograms of row>>7 and col>>8; H layout [bucket][block]
__global__ __launch_bounds__(256) void k_hist(const int* __restrict__ row,
                                              const int* __restrict__ col,
                                              int* __restrict__ Hr,
                                              int* __restrict__ Hc,
                                              int e, int nblk, int nbr, int nbc) {
    __shared__ int hr[1024];
    __shared__ int hc[512];
    int t = threadIdx.x;
    for (int i = t; i < 1024; i += 256) hr[i] = 0;
    for (int i = t; i < 512; i += 256) hc[i] = 0;
    __syncthreads();
    int base = blockIdx.x * EC;
#pragma unroll
    for (int j = 0; j < EC / 256; ++j) {
        int i = base + t + j * 256;
        if (i < e) {
            atomicAdd(&hr[row[i] >> 7], 1);
            atomicAdd(&hc[col[i] >> 8], 1);
        }
    }
    __syncthreads();
    for (int b = t; b < nbr; b += 256) Hr[(size_t)b * nblk + blockIdx.x] = hr[b];
    for (int b = t; b < nbc; b += 256) Hc[(size_t)b * nblk + blockIdx.x] = hc[b];
}

// fused: exclusive scan of Hr rows (blocks [0,nbr)) and Hc rows (blocks
// [nbr, nbr+nbc)); per-bucket totals to BtotR/BtotC. nblk<=512.
__global__ __launch_bounds__(256) void k_scanH2(int* __restrict__ Hr,
                                                int* __restrict__ Hc,
                                                int* __restrict__ BtotR,
                                                int* __restrict__ BtotC,
                                                int nblk, int nbr) {
    __shared__ int vals[512];
    __shared__ int part[256];
    int t = threadIdx.x;
    int bb = blockIdx.x;
    int* Hb;
    int* Btot;
    if (bb < nbr) {
        Hb = Hr + (size_t)bb * nblk;
        Btot = BtotR + bb;
    } else {
        Hb = Hc + (size_t)(bb - nbr) * nblk;
        Btot = BtotC + (bb - nbr);
    }
    for (int i = t; i < nblk; i += 256) vals[i] = Hb[i];
    __syncthreads();
    int c0 = t * 2;
    int s = 0;
#pragma unroll
    for (int j = 0; j < 2; ++j)
        if (c0 + j < nblk) s += vals[c0 + j];
    part[t] = s;
    __syncthreads();
    for (int d = 1; d < 256; d <<= 1) {
        int add = (t >= d) ? part[t - d] : 0;
        __syncthreads();
        part[t] += add;
        __syncthreads();
    }
    int run = part[t] - s;
#pragma unroll
    for (int j = 0; j < 2; ++j) {
        int i = c0 + j;
        if (i < nblk) {
            int v = vals[i];
            Hb[i] = run;
            run += v;
        }
    }
    if (t == 255) *Btot = part[255];
}

// fused: block 0 scans BtotR->BbR, block 1 scans BtotC->BbC
__global__ __launch_bounds__(256) void k_base2(const int* __restrict__ BtotR,
                                               int* __restrict__ BbR, int nbr,
                                               const int* __restrict__ BtotC,
                                               int* __restrict__ BbC, int nbc) {
    const int* Btot = (blockIdx.x == 0) ? BtotR : BtotC;
    int* Bbase = (blockIdx.x == 0) ? BbR : BbC;
    int nb = (blockIdx.x == 0) ? nbr : nbc;
    __shared__ int part[256];
    __shared__ int carry;
    int t = threadIdx.x;
    if (t == 0) carry = 0;
    __syncthreads();
    for (int base = 0; base < nb; base += 256) {
        int i = base + t;
        int v = (i < nb) ? Btot[i] : 0;
        part[t] = v;
        __syncthreads();
        for (int d = 1; d < 256; d <<= 1) {
            int add = (t >= d) ? part[t - d] : 0;
            __syncthreads();
            part[t] += add;
            __syncthreads();
        }
        if (i < nb) Bbase[i] = carry + part[t] - v;
        __syncthreads();
        if (t == 0) carry += part[255];
        __syncthreads();
    }
    if (t == 0) Bbase[nb] = carry;
}

// scatter edges into c-bucketed ebc (payload r<<8|c_low) and r-bucketed ebr
// (payload c<<7|r_low) using LDS cursors; plain stores, no global atomics
__global__ __launch_bounds__(256) void k_scatter_dual(
    const int* __restrict__ row, const int* __restrict__ col,
    const int* __restrict__ Hr, const int* __restrict__ Hc,
    const int* __restrict__ BbR, const int* __restrict__ BbC,
    int* __restrict__ ebr, int* __restrict__ ebc,
    int e, int nblk, int nbr, int nbc) {
    __shared__ int curr[1024];
    __shared__ int curc[512];
    int t = threadIdx.x;
    int blk = blockIdx.x;
    for (int b = t; b < nbr; b += 256) curr[b] = BbR[b] + Hr[(size_t)b * nblk + blk];
    for (int b = t; b < nbc; b += 256) curc[b] = BbC[b] + Hc[(size_t)b * nblk + blk];
    __syncthreads();
    int base = blk * EC;
#pragma unroll
    for (int j = 0; j < EC / 256; ++j) {
        int i = base + t + j * 256;
        if (i < e) {
            int r = row[i], c = col[i];
            int pr = atomicAdd(&curr[r >> 7], 1);
            ebr[pr] = (c << 7) | (r & 127);
            int pc = atomicAdd(&curc[c >> 8], 1);
            ebc[pc] = (r << 8) | (c & 255);
        }
    }
}

// block per col-bucket: exp sums into LDS, write rden (no global atomics)
__global__ __launch_bounds__(256) void k_denom_b(const int* __restrict__ ebc,
                                                 const int* __restrict__ BbC,
                                                 const float* __restrict__ s_src,
                                                 const float* __restrict__ s_dst,
                                                 float* __restrict__ rden, int n) {
    __shared__ float acc[BSC * 4];
    __shared__ float sd[BSC * 4];
    int t = threadIdx.x;
    int b = blockIdx.x;
    int cbase = b << 8;
    for (int i = t; i < BSC * 4; i += 256) {
        acc[i] = 0.0f;
        int c4 = cbase * 4 + i;
        sd[i] = (c4 < n * 4) ? s_dst[c4] : 0.0f;
    }
    __syncthreads();
    int start = BbC[b], end = BbC[b + 1];
    for (int i = start + t; i < end; i += 256) {
        int p = ebc[i];
        int r = p >> 8, cl = p & 255;
        float4 ss = *(const float4*)(s_src + (size_t)r * 4);
        atomicAdd(&acc[cl * 4 + 0], __expf(LRELU(ss.x + sd[cl * 4 + 0])));
        atomicAdd(&acc[cl * 4 + 1], __expf(LRELU(ss.y + sd[cl * 4 + 1])));
        atomicAdd(&acc[cl * 4 + 2], __expf(LRELU(ss.z + sd[cl * 4 + 2])));
        atomicAdd(&acc[cl * 4 + 3], __expf(LRELU(ss.w + sd[cl * 4 + 3])));
    }
    __syncthreads();
    for (int i = t; i < BSC * 4; i += 256) {
        int c4 = cbase * 4 + i;
        if (c4 < n * 4) rden[c4] = 1.0f / (acc[i] + 1e-16f);
    }
}

// level-2 counting sort within row-bucket: ebr -> row-sorted packed int2{c<<6,w},
// writes global rowptr; w computed here (thread-per-edge, independent loads)
__global__ __launch_bounds__(256) void k_sort2(const int* __restrict__ ebr,
                                               const int* __restrict__ BbR,
                                               const float* __restrict__ s_src,
                                               const float* __restrict__ s_dst,
                                               const float* __restrict__ rden,
                                               int* __restrict__ rowptr,
                                               int2* __restrict__ cwp,
                                               int n, int e) {
    __shared__ int cnt[BSR];
    __shared__ int pfx[BSR];
    __shared__ int cur[BSR];
    __shared__ float ssh[BSR * 4];
    int t = threadIdx.x;
    int b = blockIdx.x;
    int rbase = b << 7;
    if (t < BSR) cnt[t] = 0;
    for (int i = t; i < BSR * 4; i += 256) {
        int g = rbase * 4 + i;
        ssh[i] = (g < n * 4) ? s_src[g] : 0.0f;
    }
    __syncthreads();
    int start = BbR[b], end = BbR[b + 1];
    for (int i = start + t; i < end; i += 256)
        atomicAdd(&cnt[ebr[i] & 127], 1);
    __syncthreads();
    if (t < BSR) pfx[t] = cnt[t];
    __syncthreads();
    for (int d = 1; d < BSR; d <<= 1) {
        int v = (t < BSR && t >= d) ? pfx[t - d] : 0;
        __syncthreads();
        if (t < BSR) pfx[t] += v;
        __syncthreads();
    }
    if (t < BSR) {
        int excl = start + pfx[t] - cnt[t];
        cur[t] = excl;
        int r = rbase + t;
        if (r < n) rowptr[r] = excl;
    }
    if (b == 0 && t == 0) rowptr[n] = e;
    __syncthreads();
    for (int i = start + t; i < end; i += 256) {
        int p = ebr[i];
        int rl = p & 127, c = p >> 7;
        float4 sd = *(const float4*)(s_dst + (size_t)c * 4);
        float4 rd = *(const float4*)(rden + (size_t)c * 4);
        float wv = __expf(LRELU(ssh[rl * 4 + 0] + sd.x)) * rd.x +
                   __expf(LRELU(ssh[rl * 4 + 1] + sd.y)) * rd.y +
                   __expf(LRELU(ssh[rl * 4 + 2] + sd.z)) * rd.z +
                   __expf(LRELU(ssh[rl * 4 + 3] + sd.w)) * rd.w;
        int pos = atomicAdd(&cur[rl], 1);
        // c pre-shifted to element offset (c*64) for k_aggr's 32-bit addressing
        cwp[pos] = make_int2(c << 6, __float_as_int(0.25f * wv));
    }
}

// R15 wave-per-row CSR gather-reduce: 8 groups x 8 lanes, each group gathers a
// different edge's 128B row as uint4 (16B/lane = 8 bf16). SLOTS=4 unrolled ->
// up to 32 edges in flight; slots gated by k<nk (wave-uniform skip). Gather
// offset = cw.x (pre-shifted c*64) + lane elem offset: one 32-bit add.
__global__ __launch_bounds__(256) void k_aggr(const int* __restrict__ rowptr,
                                              const int2* __restrict__ cwp,
                                              const unsigned short* __restrict__ xt16,
                                              float* __restrict__ out, int n, int e) {
    int r = blockIdx.x * 4 + (threadIdx.x >> 6);
    if (r >= n) return;
    int lane = threadIdx.x & 63;
    int g = lane >> 3;          // edge group 0..7
    unsigned le = (lane & 7) << 3;  // covers cols [le, le+8)
    int start = rowptr[r], end = rowptr[r + 1];
    float acc[8];
#pragma unroll
    for (int j = 0; j < 8; ++j) acc[j] = 0.0f;
    for (int base = start; base < end; base += SLOTS * 8) {
        int m = end - base;
        if (m > SLOTS * 8) m = SLOTS * 8;
        int nk = (m + 7) >> 3;  // slots needed (wave-uniform)
        uint4 u[SLOTS];
        float wv[SLOTS];
#pragma unroll
        for (int k = 0; k < SLOTS; ++k) {
            if (k < nk) {
                int idx = base + k * 8 + g;
                int idc = idx < e ? idx : e - 1;  // stay in-buffer
                int2 cw = cwp[idc];              // 8B meta, broadcast in group
                wv[k] = (idx < end) ? __int_as_float(cw.y) : 0.0f;
                u[k] = *(const uint4*)(xt16 + ((unsigned)cw.x + le));
            }
        }
#pragma unroll
        for (int k = 0; k < SLOTS; ++k) {
            if (k < nk) {
                acc[0] = fmaf(wv[k], bflo(u[k].x), acc[0]);
                acc[1] = fmaf(wv[k], bfhi(u[k].x), acc[1]);
                acc[2] = fmaf(wv[k], bflo(u[k].y), acc[2]);
                acc[3] = fmaf(wv[k], bfhi(u[k].y), acc[3]);
                acc[4] = fmaf(wv[k], bflo(u[k].z), acc[4]);
                acc[5] = fmaf(wv[k], bfhi(u[k].z), acc[5]);
                acc[6] = fmaf(wv[k], bflo(u[k].w), acc[6]);
                acc[7] = fmaf(wv[k], bfhi(u[k].w), acc[7]);
            }
        }
    }
    // combine the 8 groups' partial sums (lane bits 3,4,5)
#pragma unroll
    for (int off = 8; off <= 32; off <<= 1) {
#pragma unroll
        for (int j = 0; j < 8; ++j) acc[j] += __shfl_xor(acc[j], off, 64);
    }
    if (lane < 8) {
        float4 a0 = {acc[0], acc[1], acc[2], acc[3]};
        float4 a1 = {acc[4], acc[5], acc[6], acc[7]};
        *(float4*)(out + (size_t)r * 64 + le) = a0;
        *(float4*)(out + (size_t)r * 64 + le + 4) = a1;
    }
}

extern "C" void kernel_launch(void* const* d_in, const int* in_sizes, int n_in,
                              void* d_out, int out_size, void* d_ws, size_t ws_size,
                              hipStream_t stream) {
    const float* x = (const float*)d_in[0];
    const int* ei = (const int*)d_in[1];
    // d_in[2] = edge_weight: unused by the reference
    const float* W = (const float*)d_in[3];
    const float* a = (const float*)d_in[4];
    int n = in_sizes[0] / 64;
    int e = in_sizes[1] / 2;
    const int* row = ei;
    const int* col = ei + e;
    float* out = (float*)d_out;

    int nblk = (e + EC - 1) / EC;       // 391 (<=512 for k_scanH2)
    int nbr = (n + BSR - 1) / BSR;      // 782 (<=1024)
    int nbc = (n + BSC - 1) / BSC;      // 391 (<=512)

    size_t o = 0;
    auto take = [&](size_t cnt) {
        size_t p = o;
        o += (cnt + 3) & ~(size_t)3;
        return p;
    };
    int* wsi = (int*)d_ws;
    unsigned short* xt16 = (unsigned short*)(wsi + take((size_t)n * 32));  // n*64 bf16
    float* s_src = (float*)(wsi + take((size_t)n * 4));
    float* s_dst = (float*)(wsi + take((size_t)n * 4));
    float* rden = (float*)(wsi + take((size_t)n * 4));
    int* Hr = wsi + take((size_t)nbr * nblk);
    int* Hc = wsi + take((size_t)nbc * nblk);
    int* BtotR = wsi + take(nbr);
    int* BbR = wsi + take(nbr + 1);
    int* BtotC = wsi + take(nbc);
    int* BbC = wsi + take(nbc + 1);
    int* ebr = wsi + take(e);
    int* cwbuf = wsi + take((size_t)2 * e);  // first e ints double as ebc
    int* ebc = cwbuf;            // dead after k_denom_b; k_sort2 overwrites as int2
    int2* cwp = (int2*)cwbuf;
    int* rowptr = wsi + take(n + 1);

    // Fold 4-step (q,p) <- (q+0.25p, p-0.25q): xt = aq*x + bq*(x@W^T)
    float aq = 1.f, bq = 0.f, ap = 0.f, bp = 1.f;
    for (int i = 0; i < 4; ++i) {
        float naq = aq + 0.25f * ap, nbq = bq + 0.25f * bp;
        float nap = ap - 0.25f * aq, nbp = bp - 0.25f * bq;
        aq = naq; bq = nbq; ap = nap; bp = nbp;
    }

    k_node<<<(n + NPB - 1) / NPB, 256, 0, stream>>>(x, W, a, xt16, s_src, s_dst,
                                                    n, aq, bq);
    k_hist<<<nblk, 256, 0, stream>>>(row, col, Hr, Hc, e, nblk, nbr, nbc);
    k_scanH2<<<nbr + nbc, 256, 0, stream>>>(Hr, Hc, BtotR, BtotC, nblk, nbr);
    k_base2<<<2, 256, 0, stream>>>(BtotR, BbR, nbr, BtotC, BbC, nbc);
    k_scatter_dual<<<nblk, 256, 0, stream>>>(row, col, Hr, Hc, BbR, BbC,
                                             ebr, ebc, e, nblk, nbr, nbc);
    k_denom_b<<<nbc, 256, 0, stream>>>(ebc, BbC, s_src, s_dst, rden, n);
    k_sort2<<<nbr, 256, 0, stream>>>(ebr, BbR, s_src, s_dst, rden,
                                     rowptr, cwp, n, e);
    k_aggr<<<(n + 3) / 4, 256, 0, stream>>>(rowptr, cwp, xt16, out, n, e);
}

// Round 5
// 300.753 us; speedup vs baseline: 1.0819x; 1.0253x over previous
//
#include <hip/hip_runtime.h>
#include <hip/hip_bf16.h>

// HamGraphConvolution: N=100k nodes, D=64 feats, H=4 heads (DK=16), E=1.6M edges.
// xt = c1*x + c2*(x@W^T)  (Hamiltonian 4-step linear recurrence folded on host)
// GAT-style attention normalized over col, aggregated over row.
// Softmax max-subtraction skipped: shift-invariant, eps 1e-16 unreachable.
// R11: xt stored bf16 (halves gather traffic), scores fp32.
// R12 FAILED (block-per-bucket fused aggr, 12x slower): collapsed TLP to 6.2K
//     waves with serial per-wave latency chains. Reverted.
// R13: k_aggr 4x16-lane groups, 32 edges in flight, no serial tail: 53->50us.
// R14 FAILED (4 rows/wave serial): wave count 4x down -> latency-bound kernel
//     starved (VALU 50->30%, dur +20%). Wave-per-row parallelism is sacred.
// R15: k_aggr 8 groups x 8 lanes, 16B/lane gathers: 50->~45us; k_node now top.
// R16: k_node was LDS-broadcast-bound (128 wave-uniform ds_read_b128/wave to
//     move the x-tile = 16B/instr through the LDS port; ~1.5K cyc vs 1K FMA).
//     Rewritten as MFMA GEMM (16x16x32 bf16, wave-per-16-nodes, no LDS):
//     W + geff held in B-frags (loaded once/wave from global); scores folded
//     into the MFMA as 16 extra B-cols via geff = c1*g + c2*W^T g (hi/lo bf16
//     split), precomputed by 1-block k_geff. Epilogue re-reads x (L1-hot).

#define LRELU(v) ((v) > 0.0f ? (v) : 0.2f * (v))

#define EC 4096      // edges per hist/scatter block
#define BSC 256      // col-bucket size (shift 8)
#define BSR 128      // row-bucket size (shift 7)
#define SLOTS 4      // unrolled edge slots in k_aggr (8 edges each)

typedef __attribute__((ext_vector_type(8))) short bf16x8;
typedef __attribute__((ext_vector_type(4))) float f32x4;

__device__ __forceinline__ float bf16_to_f32(unsigned short u) {
    return __uint_as_float((unsigned int)u << 16);
}
__device__ __forceinline__ float bflo(unsigned int u) {
    return __uint_as_float(u << 16);
}
__device__ __forceinline__ float bfhi(unsigned int u) {
    return __uint_as_float(u & 0xFFFF0000u);
}
__device__ __forceinline__ unsigned short f32_to_bf16(float f) {
    __hip_bfloat16 h = __float2bfloat16(f);  // RTN
    return *reinterpret_cast<unsigned short*>(&h);
}

// geff[h][k]: score folding vectors. s_src[n][h] = x[n] . (c1*g_h + c2*W^T g_h)
// where g_h[k'] = a_src[k'&15]*[k'>>4==h]. Stored bf16 hi/lo as 16 B-columns:
// col 0-3 src-hi, 4-7 dst-hi, 8-11 src-lo, 12-15 dst-lo.
__global__ __launch_bounds__(256) void k_geff(const float* __restrict__ W,
                                              const float* __restrict__ a,
                                              unsigned short* __restrict__ geff16,
                                              float c1, float c2) {
    int t = threadIdx.x;
    int k = t & 63, h = t >> 6;  // h = 0..3
    float ssrc = 0.0f, sdst = 0.0f;
#pragma unroll
    for (int d = 0; d < 16; ++d) {
        float w = W[(h * 16 + d) * 64 + k];
        ssrc += w * a[d];
        sdst += w * a[16 + d];
    }
    float gsrc = c2 * ssrc, gdst = c2 * sdst;
    if ((k >> 4) == h) {
        gsrc += c1 * a[k & 15];
        gdst += c1 * a[16 + (k & 15)];
    }
    unsigned short sh = f32_to_bf16(gsrc);
    unsigned short sl = f32_to_bf16(gsrc - bf16_to_f32(sh));
    unsigned short dh = f32_to_bf16(gdst);
    unsigned short dl = f32_to_bf16(gdst - bf16_to_f32(dh));
    geff16[h * 64 + k] = sh;
    geff16[(4 + h) * 64 + k] = dh;
    geff16[(8 + h) * 64 + k] = sl;
    geff16[(12 + h) * 64 + k] = dl;
}

// R16 MFMA node kernel: wave per 16 nodes, 4 waves/block (64 nodes).
// A = x-tile (16x64 bf16, 2 K-step frags from global), B = {W^T 4 col-tiles,
// geff 1 col-tile} held in regs, 10 mfma/wave. C-layout (m89, verified):
// col=lane&15, row=(lane>>4)*4+reg.
__global__ __launch_bounds__(256) void k_node(const float* __restrict__ x,
                                              const float* __restrict__ W,
                                              const unsigned short* __restrict__ geff16,
                                              unsigned short* __restrict__ xt16,
                                              float* __restrict__ s_src,
                                              float* __restrict__ s_dst,
                                              int n, float c1, float c2) {
    int wave = threadIdx.x >> 6;
    int lane = threadIdx.x & 63;
    int nb = blockIdx.x * 64 + wave * 16;
    if (nb >= n) return;
    int colg = lane & 15;     // A: row idx; B: col idx; C: col idx
    int grp = lane >> 4;      // k-slice group (A/B); row group (C)
    int k0 = grp << 3;        // k offset 0/8/16/24 within 32-k step

    // B-frags: W^T col-tiles (W[ct*16+colg][k]) + geff tile, once per wave
    bf16x8 wf[4][2];
#pragma unroll
    for (int ct = 0; ct < 4; ++ct) {
#pragma unroll
        for (int ks = 0; ks < 2; ++ks) {
            const float* wr = W + (size_t)(ct * 16 + colg) * 64 + k0 + ks * 32;
            float4 w0 = *(const float4*)(wr);
            float4 w1 = *(const float4*)(wr + 4);
            bf16x8 f;
            f[0] = (short)f32_to_bf16(w0.x); f[1] = (short)f32_to_bf16(w0.y);
            f[2] = (short)f32_to_bf16(w0.z); f[3] = (short)f32_to_bf16(w0.w);
            f[4] = (short)f32_to_bf16(w1.x); f[5] = (short)f32_to_bf16(w1.y);
            f[6] = (short)f32_to_bf16(w1.z); f[7] = (short)f32_to_bf16(w1.w);
            wf[ct][ks] = f;
        }
    }
    bf16x8 gf[2];
#pragma unroll
    for (int ks = 0; ks < 2; ++ks)
        gf[ks] = *(const bf16x8*)(geff16 + colg * 64 + k0 + ks * 32);

    // A-frags: x rows nb+colg, bf16 (RTN)
    int arow = nb + colg;
    if (arow >= n) arow = n - 1;
    const float* xr = x + (size_t)arow * 64 + k0;
    bf16x8 af[2];
#pragma unroll
    for (int ks = 0; ks < 2; ++ks) {
        float4 x0 = *(const float4*)(xr + ks * 32);
        float4 x1 = *(const float4*)(xr + ks * 32 + 4);
        bf16x8 f;
        f[0] = (short)f32_to_bf16(x0.x); f[1] = (short)f32_to_bf16(x0.y);
        f[2] = (short)f32_to_bf16(x0.z); f[3] = (short)f32_to_bf16(x0.w);
        f[4] = (short)f32_to_bf16(x1.x); f[5] = (short)f32_to_bf16(x1.y);
        f[6] = (short)f32_to_bf16(x1.z); f[7] = (short)f32_to_bf16(x1.w);
        af[ks] = f;
    }

    f32x4 acc[5];
#pragma unroll
    for (int i = 0; i < 5; ++i) acc[i] = (f32x4){0.f, 0.f, 0.f, 0.f};
#pragma unroll
    for (int ct = 0; ct < 4; ++ct) {
        acc[ct] = __builtin_amdgcn_mfma_f32_16x16x32_bf16(af[0], wf[ct][0], acc[ct], 0, 0, 0);
        acc[ct] = __builtin_amdgcn_mfma_f32_16x16x32_bf16(af[1], wf[ct][1], acc[ct], 0, 0, 0);
    }
    acc[4] = __builtin_amdgcn_mfma_f32_16x16x32_bf16(af[0], gf[0], acc[4], 0, 0, 0);
    acc[4] = __builtin_amdgcn_mfma_f32_16x16x32_bf16(af[1], gf[1], acc[4], 0, 0, 0);

    // epilogue: xt = c1*x + c2*p (x re-read, L1-hot); C row = grp*4+rr
#pragma unroll
    for (int ct = 0; ct < 4; ++ct) {
        int col = ct * 16 + colg;
#pragma unroll
        for (int rr = 0; rr < 4; ++rr) {
            int node = nb + grp * 4 + rr;
            if (node < n) {
                float xv = x[(size_t)node * 64 + col];
                float xtv = c1 * xv + c2 * acc[ct][rr];
                xt16[(size_t)node * 64 + col] = f32_to_bf16(xtv);
            }
        }
    }
    // scores: tile 4, hi(cols 0-7) + lo(cols 8-15)
#pragma unroll
    for (int rr = 0; rr < 4; ++rr) {
        float v = acc[4][rr];
        float tot = v + __shfl_xor(v, 8, 64);
        int node = nb + grp * 4 + rr;
        if (node < n) {
            if (colg < 4) s_src[node * 4 + colg] = tot;
            else if (colg < 8) s_dst[node * 4 + (colg - 4)] = tot;
        }
    }
}

// per-block LDS histograms of row>>7 and col>>8; H layout [bucket][block]
__global__ __launch_bounds__(256) void k_hist(const int* __restrict__ row,
                                              const int* __restrict__ col,
                                              int* __restrict__ Hr,
                                              int* __restrict__ Hc,
                                              int e, int nblk, int nbr, int nbc) {
    __shared__ int hr[1024];
    __shared__ int hc[512];
    int t = threadIdx.x;
    for (int i = t; i < 1024; i += 256) hr[i] = 0;
    for (int i = t; i < 512; i += 256) hc[i] = 0;
    __syncthreads();
    int base = blockIdx.x * EC;
#pragma unroll
    for (int j = 0; j < EC / 256; ++j) {
        int i = base + t + j * 256;
        if (i < e) {
            atomicAdd(&hr[row[i] >> 7], 1);
            atomicAdd(&hc[col[i] >> 8], 1);
        }
    }
    __syncthreads();
    for (int b = t; b < nbr; b += 256) Hr[(size_t)b * nblk + blockIdx.x] = hr[b];
    for (int b = t; b < nbc; b += 256) Hc[(size_t)b * nblk + blockIdx.x] = hc[b];
}

// fused: exclusive scan of Hr rows (blocks [0,nbr)) and Hc rows (blocks
// [nbr, nbr+nbc)); per-bucket totals to BtotR/BtotC. nblk<=512.
__global__ __launch_bounds__(256) void k_scanH2(int* __restrict__ Hr,
                                                int* __restrict__ Hc,
                                                int* __restrict__ BtotR,
                                                int* __restrict__ BtotC,
                                                int nblk, int nbr) {
    __shared__ int vals[512];
    __shared__ int part[256];
    int t = threadIdx.x;
    int bb = blockIdx.x;
    int* Hb;
    int* Btot;
    if (bb < nbr) {
        Hb = Hr + (size_t)bb * nblk;
        Btot = BtotR + bb;
    } else {
        Hb = Hc + (size_t)(bb - nbr) * nblk;
        Btot = BtotC + (bb - nbr);
    }
    for (int i = t; i < nblk; i += 256) vals[i] = Hb[i];
    __syncthreads();
    int c0 = t * 2;
    int s = 0;
#pragma unroll
    for (int j = 0; j < 2; ++j)
        if (c0 + j < nblk) s += vals[c0 + j];
    part[t] = s;
    __syncthreads();
    for (int d = 1; d < 256; d <<= 1) {
        int add = (t >= d) ? part[t - d] : 0;
        __syncthreads();
        part[t] += add;
        __syncthreads();
    }
    int run = part[t] - s;
#pragma unroll
    for (int j = 0; j < 2; ++j) {
        int i = c0 + j;
        if (i < nblk) {
            int v = vals[i];
            Hb[i] = run;
            run += v;
        }
    }
    if (t == 255) *Btot = part[255];
}

// fused: block 0 scans BtotR->BbR, block 1 scans BtotC->BbC
__global__ __launch_bounds__(256) void k_base2(const int* __restrict__ BtotR,
                                               int* __restrict__ BbR, int nbr,
                                               const int* __restrict__ BtotC,
                                               int* __restrict__ BbC, int nbc) {
    const int* Btot = (blockIdx.x == 0) ? BtotR : BtotC;
    int* Bbase = (blockIdx.x == 0) ? BbR : BbC;
    int nb = (blockIdx.x == 0) ? nbr : nbc;
    __shared__ int part[256];
    __shared__ int carry;
    int t = threadIdx.x;
    if (t == 0) carry = 0;
    __syncthreads();
    for (int base = 0; base < nb; base += 256) {
        int i = base + t;
        int v = (i < nb) ? Btot[i] : 0;
        part[t] = v;
        __syncthreads();
        for (int d = 1; d < 256; d <<= 1) {
            int add = (t >= d) ? part[t - d] : 0;
            __syncthreads();
            part[t] += add;
            __syncthreads();
        }
        if (i < nb) Bbase[i] = carry + part[t] - v;
        __syncthreads();
        if (t == 0) carry += part[255];
        __syncthreads();
    }
    if (t == 0) Bbase[nb] = carry;
}

// scatter edges into c-bucketed ebc (payload r<<8|c_low) and r-bucketed ebr
// (payload c<<7|r_low) using LDS cursors; plain stores, no global atomics
__global__ __launch_bounds__(256) void k_scatter_dual(
    const int* __restrict__ row, const int* __restrict__ col,
    const int* __restrict__ Hr, const int* __restrict__ Hc,
    const int* __restrict__ BbR, const int* __restrict__ BbC,
    int* __restrict__ ebr, int* __restrict__ ebc,
    int e, int nblk, int nbr, int nbc) {
    __shared__ int curr[1024];
    __shared__ int curc[512];
    int t = threadIdx.x;
    int blk = blockIdx.x;
    for (int b = t; b < nbr; b += 256) curr[b] = BbR[b] + Hr[(size_t)b * nblk + blk];
    for (int b = t; b < nbc; b += 256) curc[b] = BbC[b] + Hc[(size_t)b * nblk + blk];
    __syncthreads();
    int base = blk * EC;
#pragma unroll
    for (int j = 0; j < EC / 256; ++j) {
        int i = base + t + j * 256;
        if (i < e) {
            int r = row[i], c = col[i];
            int pr = atomicAdd(&curr[r >> 7], 1);
            ebr[pr] = (c << 7) | (r & 127);
            int pc = atomicAdd(&curc[c >> 8], 1);
            ebc[pc] = (r << 8) | (c & 255);
        }
    }
}

// block per col-bucket: exp sums into LDS, write rden (no global atomics)
__global__ __launch_bounds__(256) void k_denom_b(const int* __restrict__ ebc,
                                                 const int* __restrict__ BbC,
                                                 const float* __restrict__ s_src,
                                                 const float* __restrict__ s_dst,
                                                 float* __restrict__ rden, int n) {
    __shared__ float acc[BSC * 4];
    __shared__ float sd[BSC * 4];
    int t = threadIdx.x;
    int b = blockIdx.x;
    int cbase = b << 8;
    for (int i = t; i < BSC * 4; i += 256) {
        acc[i] = 0.0f;
        int c4 = cbase * 4 + i;
        sd[i] = (c4 < n * 4) ? s_dst[c4] : 0.0f;
    }
    __syncthreads();
    int start = BbC[b], end = BbC[b + 1];
    for (int i = start + t; i < end; i += 256) {
        int p = ebc[i];
        int r = p >> 8, cl = p & 255;
        float4 ss = *(const float4*)(s_src + (size_t)r * 4);
        atomicAdd(&acc[cl * 4 + 0], __expf(LRELU(ss.x + sd[cl * 4 + 0])));
        atomicAdd(&acc[cl * 4 + 1], __expf(LRELU(ss.y + sd[cl * 4 + 1])));
        atomicAdd(&acc[cl * 4 + 2], __expf(LRELU(ss.z + sd[cl * 4 + 2])));
        atomicAdd(&acc[cl * 4 + 3], __expf(LRELU(ss.w + sd[cl * 4 + 3])));
    }
    __syncthreads();
    for (int i = t; i < BSC * 4; i += 256) {
        int c4 = cbase * 4 + i;
        if (c4 < n * 4) rden[c4] = 1.0f / (acc[i] + 1e-16f);
    }
}

// level-2 counting sort within row-bucket: ebr -> row-sorted packed int2{c<<6,w},
// writes global rowptr; w computed here (thread-per-edge, independent loads)
__global__ __launch_bounds__(256) void k_sort2(const int* __restrict__ ebr,
                                               const int* __restrict__ BbR,
                                               const float* __restrict__ s_src,
                                               const float* __restrict__ s_dst,
                                               const float* __restrict__ rden,
                                               int* __restrict__ rowptr,
                                               int2* __restrict__ cwp,
                                               int n, int e) {
    __shared__ int cnt[BSR];
    __shared__ int pfx[BSR];
    __shared__ int cur[BSR];
    __shared__ float ssh[BSR * 4];
    int t = threadIdx.x;
    int b = blockIdx.x;
    int rbase = b << 7;
    if (t < BSR) cnt[t] = 0;
    for (int i = t; i < BSR * 4; i += 256) {
        int g = rbase * 4 + i;
        ssh[i] = (g < n * 4) ? s_src[g] : 0.0f;
    }
    __syncthreads();
    int start = BbR[b], end = BbR[b + 1];
    for (int i = start + t; i < end; i += 256)
        atomicAdd(&cnt[ebr[i] & 127], 1);
    __syncthreads();
    if (t < BSR) pfx[t] = cnt[t];
    __syncthreads();
    for (int d = 1; d < BSR; d <<= 1) {
        int v = (t < BSR && t >= d) ? pfx[t - d] : 0;
        __syncthreads();
        if (t < BSR) pfx[t] += v;
        __syncthreads();
    }
    if (t < BSR) {
        int excl = start + pfx[t] - cnt[t];
        cur[t] = excl;
        int r = rbase + t;
        if (r < n) rowptr[r] = excl;
    }
    if (b == 0 && t == 0) rowptr[n] = e;
    __syncthreads();
    for (int i = start + t; i < end; i += 256) {
        int p = ebr[i];
        int rl = p & 127, c = p >> 7;
        float4 sd = *(const float4*)(s_dst + (size_t)c * 4);
        float4 rd = *(const float4*)(rden + (size_t)c * 4);
        float wv = __expf(LRELU(ssh[rl * 4 + 0] + sd.x)) * rd.x +
                   __expf(LRELU(ssh[rl * 4 + 1] + sd.y)) * rd.y +
                   __expf(LRELU(ssh[rl * 4 + 2] + sd.z)) * rd.z +
                   __expf(LRELU(ssh[rl * 4 + 3] + sd.w)) * rd.w;
        int pos = atomicAdd(&cur[rl], 1);
        // c pre-shifted to element offset (c*64) for k_aggr's 32-bit addressing
        cwp[pos] = make_int2(c << 6, __float_as_int(0.25f * wv));
    }
}

// R15 wave-per-row CSR gather-reduce: 8 groups x 8 lanes, each group gathers a
// different edge's 128B row as uint4 (16B/lane = 8 bf16). SLOTS=4 unrolled ->
// up to 32 edges in flight; slots gated by k<nk (wave-uniform skip). Gather
// offset = cw.x (pre-shifted c*64) + lane elem offset: one 32-bit add.
__global__ __launch_bounds__(256) void k_aggr(const int* __restrict__ rowptr,
                                              const int2* __restrict__ cwp,
                                              const unsigned short* __restrict__ xt16,
                                              float* __restrict__ out, int n, int e) {
    int r = blockIdx.x * 4 + (threadIdx.x >> 6);
    if (r >= n) return;
    int lane = threadIdx.x & 63;
    int g = lane >> 3;          // edge group 0..7
    unsigned le = (lane & 7) << 3;  // covers cols [le, le+8)
    int start = rowptr[r], end = rowptr[r + 1];
    float acc[8];
#pragma unroll
    for (int j = 0; j < 8; ++j) acc[j] = 0.0f;
    for (int base = start; base < end; base += SLOTS * 8) {
        int m = end - base;
        if (m > SLOTS * 8) m = SLOTS * 8;
        int nk = (m + 7) >> 3;  // slots needed (wave-uniform)
        uint4 u[SLOTS];
        float wv[SLOTS];
#pragma unroll
        for (int k = 0; k < SLOTS; ++k) {
            if (k < nk) {
                int idx = base + k * 8 + g;
                int idc = idx < e ? idx : e - 1;  // stay in-buffer
                int2 cw = cwp[idc];              // 8B meta, broadcast in group
                wv[k] = (idx < end) ? __int_as_float(cw.y) : 0.0f;
                u[k] = *(const uint4*)(xt16 + ((unsigned)cw.x + le));
            }
        }
#pragma unroll
        for (int k = 0; k < SLOTS; ++k) {
            if (k < nk) {
                acc[0] = fmaf(wv[k], bflo(u[k].x), acc[0]);
                acc[1] = fmaf(wv[k], bfhi(u[k].x), acc[1]);
                acc[2] = fmaf(wv[k], bflo(u[k].y), acc[2]);
                acc[3] = fmaf(wv[k], bfhi(u[k].y), acc[3]);
                acc[4] = fmaf(wv[k], bflo(u[k].z), acc[4]);
                acc[5] = fmaf(wv[k], bfhi(u[k].z), acc[5]);
                acc[6] = fmaf(wv[k], bflo(u[k].w), acc[6]);
                acc[7] = fmaf(wv[k], bfhi(u[k].w), acc[7]);
            }
        }
    }
    // combine the 8 groups' partial sums (lane bits 3,4,5)
#pragma unroll
    for (int off = 8; off <= 32; off <<= 1) {
#pragma unroll
        for (int j = 0; j < 8; ++j) acc[j] += __shfl_xor(acc[j], off, 64);
    }
    if (lane < 8) {
        float4 a0 = {acc[0], acc[1], acc[2], acc[3]};
        float4 a1 = {acc[4], acc[5], acc[6], acc[7]};
        *(float4*)(out + (size_t)r * 64 + le) = a0;
        *(float4*)(out + (size_t)r * 64 + le + 4) = a1;
    }
}

extern "C" void kernel_launch(void* const* d_in, const int* in_sizes, int n_in,
                              void* d_out, int out_size, void* d_ws, size_t ws_size,
                              hipStream_t stream) {
    const float* x = (const float*)d_in[0];
    const int* ei = (const int*)d_in[1];
    // d_in[2] = edge_weight: unused by the reference
    const float* W = (const float*)d_in[3];
    const float* a = (const float*)d_in[4];
    int n = in_sizes[0] / 64;
    int e = in_sizes[1] / 2;
    const int* row = ei;
    const int* col = ei + e;
    float* out = (float*)d_out;

    int nblk = (e + EC - 1) / EC;       // 391 (<=512 for k_scanH2)
    int nbr = (n + BSR - 1) / BSR;      // 782 (<=1024)
    int nbc = (n + BSC - 1) / BSC;      // 391 (<=512)

    size_t o = 0;
    auto take = [&](size_t cnt) {
        size_t p = o;
        o += (cnt + 3) & ~(size_t)3;
        return p;
    };
    int* wsi = (int*)d_ws;
    unsigned short* xt16 = (unsigned short*)(wsi + take((size_t)n * 32));  // n*64 bf16
    float* s_src = (float*)(wsi + take((size_t)n * 4));
    float* s_dst = (float*)(wsi + take((size_t)n * 4));
    float* rden = (float*)(wsi + take((size_t)n * 4));
    unsigned short* geff16 = (unsigned short*)(wsi + take(512));  // 16x64 bf16
    int* Hr = wsi + take((size_t)nbr * nblk);
    int* Hc = wsi + take((size_t)nbc * nblk);
    int* BtotR = wsi + take(nbr);
    int* BbR = wsi + take(nbr + 1);
    int* BtotC = wsi + take(nbc);
    int* BbC = wsi + take(nbc + 1);
    int* ebr = wsi + take(e);
    int* cwbuf = wsi + take((size_t)2 * e);  // first e ints double as ebc
    int* ebc = cwbuf;            // dead after k_denom_b; k_sort2 overwrites as int2
    int2* cwp = (int2*)cwbuf;
    int* rowptr = wsi + take(n + 1);

    // Fold 4-step (q,p) <- (q+0.25p, p-0.25q): xt = aq*x + bq*(x@W^T)
    float aq = 1.f, bq = 0.f, ap = 0.f, bp = 1.f;
    for (int i = 0; i < 4; ++i) {
        float naq = aq + 0.25f * ap, nbq = bq + 0.25f * bp;
        float nap = ap - 0.25f * aq, nbp = bp - 0.25f * bq;
        aq = naq; bq = nbq; ap = nap; bp = nbp;
    }

    k_geff<<<1, 256, 0, stream>>>(W, a, geff16, aq, bq);
    k_node<<<(n + 63) / 64, 256, 0, stream>>>(x, W, geff16, xt16, s_src, s_dst,
                                              n, aq, bq);
    k_hist<<<nblk, 256, 0, stream>>>(row, col, Hr, Hc, e, nblk, nbr, nbc);
    k_scanH2<<<nbr + nbc, 256, 0, stream>>>(Hr, Hc, BtotR, BtotC, nblk, nbr);
    k_base2<<<2, 256, 0, stream>>>(BtotR, BbR, nbr, BtotC, BbC, nbc);
    k_scatter_dual<<<nblk, 256, 0, stream>>>(row, col, Hr, Hc, BbR, BbC,
                                             ebr, ebc, e, nblk, nbr, nbc);
    k_denom_b<<<nbc, 256, 0, stream>>>(ebc, BbC, s_src, s_dst, rden, n);
    k_sort2<<<nbr, 256, 0, stream>>>(ebr, BbR, s_src, s_dst, rden,
                                     rowptr, cwp, n, e);
    k_aggr<<<(n + 3) / 4, 256, 0, stream>>>(rowptr, cwp, xt16, out, n, e);
}